// Round 3
// baseline (558.680 us; speedup 1.0000x reference)
//
#include <hip/hip_runtime.h>
#include <hip/hip_bf16.h>
#include <stdint.h>

// B=32, T=512, D=1024, H=16, HD=64
#define NTOK 16384

typedef _Float16 f16;
typedef f16   f16x8 __attribute__((ext_vector_type(8)));
typedef float f32x4 __attribute__((ext_vector_type(4)));

__device__ __forceinline__ float bf2f(ushort h){
  union { uint32_t u; float f; } v; v.u = ((uint32_t)h) << 16; return v.f;
}
__device__ __forceinline__ ushort f2bf(float f){
  union { float f; uint32_t u; } v; v.f = f;
  uint32_t u = v.u;
  return (ushort)((u + 0x7FFFu + ((u >> 16) & 1u)) >> 16);  // RNE
}
__device__ __forceinline__ ushort f2h(float f){          // fp32 -> fp16 bits (RNE)
  return __builtin_bit_cast(ushort, (f16)f);
}
__device__ __forceinline__ f16x8 ld16(const ushort* p){  // 8 fp16
  uint4 u = *(const uint4*)p;
  return __builtin_bit_cast(f16x8, u);
}
// dtype-flexible fp32 load: fp32 path direct, bf16 path converts
__device__ __forceinline__ float ldf(const void* p, size_t idx, int isf32){
  if (isf32) return ((const float*)p)[idx];
  return bf2f(((const ushort*)p)[idx]);
}

// ---------------- input dtype detection --------------------------------------
// bf16-packed Wi: low ushort of each dword is a bf16 ~N(0,1/32) -> exp field in
// [100,130] nearly always. fp32 Wi: low ushort is raw mantissa -> ~12% hit.
__global__ __launch_bounds__(256) void kdetect(const uint* __restrict__ wi, int* __restrict__ flag){
  __shared__ int cnt;
  if (threadIdx.x == 0) cnt = 0;
  __syncthreads();
  uint w = wi[threadIdx.x];
  uint e = (w >> 7) & 0xFFu;
  if (e >= 100u && e <= 130u) atomicAdd(&cnt, 1);
  __syncthreads();
  if (threadIdx.x == 0) flag[0] = (cnt < 128) ? 1 : 0;
}

// ---------------- bias canonicalization -> fp32 (5120 elements) --------------
__global__ __launch_bounds__(256) void kbias(const void* bi, const void* bo,
                                             const void* bk, const void* bq, const void* bv,
                                             const int* __restrict__ flag,
                                             float* bi_f, float* bo_f, float* bqkv_f){
  int f = flag[0];
  uint id = blockIdx.x*256u + threadIdx.x;   // [0, 5120)
  if (id < 1024u)       bi_f[id]         = ldf(bi, id, f);
  else if (id < 2048u)  bo_f[id - 1024u] = ldf(bo, id - 1024u, f);
  else {
    uint j = id - 2048u;                     // [0,3072): sel*1024 + (h*64+e)
    uint sel = j >> 10, i = j & 1023u;
    const void* src = (sel == 0) ? bk : ((sel == 1) ? bq : bv);
    bqkv_f[j] = ldf(src, i, f);
  }
}

// ---------------- weight transpose -> fp16: out[c][r] = in[r][c], 1024x1024 ---
__global__ __launch_bounds__(256) void ktranspose(const void* __restrict__ in,
                                                  const int* __restrict__ flag,
                                                  ushort* __restrict__ out){
  int f = flag[0];
  uint oid = blockIdx.x*256u + threadIdx.x;
  out[oid] = f2h(ldf(in, (size_t)(oid & 1023u)*1024u + (oid >> 10), f));
}

// WqkvT[c][d] fp16, c = sel*1024 + h*64 + e ; W[sel] flat = h*65536 + d*64 + e
__global__ __launch_bounds__(256) void kqkvpack(const void* Wk, const void* Wq, const void* Wv,
                                                const int* __restrict__ flag,
                                                ushort* __restrict__ WqkvT){
  int f = flag[0];
  uint oid = blockIdx.x*256u + threadIdx.x;       // over 3072*1024
  uint c = oid >> 10, d = oid & 1023u;
  uint sel = c >> 10, cc = c & 1023u;
  const void* W = (sel == 0) ? Wk : ((sel == 1) ? Wq : Wv);
  WqkvT[oid] = f2h(ldf(W, (size_t)(cc >> 6)*65536u + d*64u + (cc & 63u), f));
}

// x -> canonical fp16 (16M elements, 8 per thread)
__global__ __launch_bounds__(256) void kcvt_x(const void* __restrict__ x,
                                              const int* __restrict__ flag,
                                              ushort* __restrict__ xh){
  int f = flag[0];
  size_t g = (size_t)(blockIdx.x*256u + threadIdx.x)*8u;
  ushort o[8];
  if (f){
    const float* xf = (const float*)x + g;
    #pragma unroll
    for (int i = 0; i < 8; ++i) o[i] = f2h(xf[i]);
  } else {
    const ushort* xb = (const ushort*)x + g;
    #pragma unroll
    for (int i = 0; i < 8; ++i) o[i] = f2h(bf2f(xb[i]));
  }
  *(uint4*)(xh + g) = *(uint4*)o;
}

// ---------------- GEMM: C[M,N] = A[M,K] @ Bt[N,K]^T + bias (fp16, m97) -------
// MODE 0: C fp16 [M,N].  MODE 1: qkv split (cols<2048 -> kq stride 2048,
// cols>=2048 -> Vt transposed [(b*16+h)*64+e][512], all fp16).  MODE 2: final
// out, dtype per flag (fp32 or bf16).
template<int MODE>
__global__ __launch_bounds__(256, 3) void kgemm(const ushort* __restrict__ A, const ushort* __restrict__ Bt,
                                                const float* __restrict__ bias, void* __restrict__ Cv,
                                                ushort* __restrict__ Vt, const int* __restrict__ dtf,
                                                int M, int N, int K){
  __shared__ ushort sA[128*32];
  __shared__ ushort sB[128*32];
  uint tid = threadIdx.x, w = tid >> 6, lane = tid & 63u, quad = lane >> 4, l15 = lane & 15u;
  uint bm = blockIdx.x, bn = blockIdx.y;
  uint wm = w >> 1, wn = w & 1u;
  f32x4 acc[4][4] = {};

  for (int k0 = 0; k0 < K; k0 += 32){
    #pragma unroll
    for (int i = 0; i < 2; ++i){
      uint c   = (w*2u + i)*64u + lane;     // 16B chunk id within tile
      uint row = c >> 2, ko = (c & 3u)*8u;  // [128][32] row-major, 4 chunks/row
      const ushort* gA = A  + (size_t)(bm*128u + row)*K + k0 + ko;
      const ushort* gB = Bt + (size_t)(bn*128u + row)*K + k0 + ko;
      __builtin_amdgcn_global_load_lds((const __attribute__((address_space(1))) void*)gA,
          (__attribute__((address_space(3))) void*)(sA + (w*2u + i)*512u), 16, 0, 0);
      __builtin_amdgcn_global_load_lds((const __attribute__((address_space(1))) void*)gB,
          (__attribute__((address_space(3))) void*)(sB + (w*2u + i)*512u), 16, 0, 0);
    }
    __syncthreads();
    f16x8 aF[4], bF[4];
    #pragma unroll
    for (int i = 0; i < 4; ++i) aF[i] = *(const f16x8*)(sA + (wm*64u + i*16u + l15)*32u + quad*8u);
    #pragma unroll
    for (int j = 0; j < 4; ++j) bF[j] = *(const f16x8*)(sB + (wn*64u + j*16u + l15)*32u + quad*8u);
    #pragma unroll
    for (int i = 0; i < 4; ++i)
      #pragma unroll
      for (int j = 0; j < 4; ++j)
        acc[i][j] = __builtin_amdgcn_mfma_f32_16x16x32_f16(aF[i], bF[j], acc[i][j], 0, 0, 0);
    __syncthreads();
  }
  int f32out = (MODE == 2) ? dtf[0] : 0;
  #pragma unroll
  for (int j = 0; j < 4; ++j){
    uint col = bn*128u + wn*64u + j*16u + l15;
    float bj = bias[col];
    #pragma unroll
    for (int i = 0; i < 4; ++i){
      uint row0 = bm*128u + wm*64u + i*16u + quad*4u;
      #pragma unroll
      for (int r = 0; r < 4; ++r){
        float val = acc[i][j][r] + bj;
        uint row = row0 + r;
        if (MODE == 0){
          ((ushort*)Cv)[(size_t)row*N + col] = f2h(val);
        } else if (MODE == 1){
          if (col < 2048u){
            ((ushort*)Cv)[(size_t)row*2048u + col] = f2h(val);
          } else {
            uint c2 = col - 2048u;           // h*64+e ; row = b*512+s
            Vt[(size_t)(((row >> 9)*16u + (c2 >> 6))*64u + (c2 & 63u))*512u + (row & 511u)] = f2h(val);
          }
        } else {
          if (f32out) ((float*)Cv)[(size_t)row*N + col] = val;
          else        ((ushort*)Cv)[(size_t)row*N + col] = f2bf(val);
        }
      }
    }
  }
}

// ---------------- fused attention ("transposed" causal, flash-style) ---------
// S[t,s] = K[t,:]·Q[s,:], keep s<=t, softmax over s, O[t,:] = sum_s P[t,s]V[s,:]
// kq: fp16 [16384][2048] (k cols 0..1023, q cols 1024..2047);
// Vt: fp16 [(b*16+h)*64+e][512]
__global__ __launch_bounds__(256, 3) void kattn(const ushort* __restrict__ kq,
                                                const ushort* __restrict__ Vt,
                                                ushort* __restrict__ Out){
  __shared__ ushort pbuf[4][16][64];
  uint tid = threadIdx.x, w = tid >> 6, lane = tid & 63u, quad = lane >> 4, l15 = lane & 15u;
  uint bh = blockIdx.x, tt = blockIdx.y;
  uint b = bh >> 4, h = bh & 15u;
  uint t0 = tt*64u;
  const float L2E = 1.44269504088896340736f;
  const float MNEG = -1.0e30f;

  f16x8 aK[2];  // K rows for this wave's 16 t's (A-operand, resident)
  {
    const ushort* kp = kq + (size_t)(b*512u + t0 + w*16u + l15)*2048u + h*64u + quad*8u;
    aK[0] = ld16(kp);
    aK[1] = ld16(kp + 32);
  }
  float m[4], l[4];
  f32x4 oacc[4];
  #pragma unroll
  for (int r = 0; r < 4; ++r){ m[r] = MNEG; l[r] = 0.f; }
  #pragma unroll
  for (int je = 0; je < 4; ++je) oacc[je] = (f32x4){0.f, 0.f, 0.f, 0.f};

  for (uint st = 0; st <= tt; ++st){
    uint s0 = st*64u;
    f32x4 sacc[4];
    #pragma unroll
    for (int j = 0; j < 4; ++j){
      const ushort* qp = kq + (size_t)(b*512u + s0 + j*16u + l15)*2048u + 1024u + h*64u + quad*8u;
      f16x8 bq0 = ld16(qp);
      f16x8 bq1 = ld16(qp + 32);
      f32x4 s = (f32x4){0.f, 0.f, 0.f, 0.f};
      s = __builtin_amdgcn_mfma_f32_16x16x32_f16(aK[0], bq0, s, 0, 0, 0);
      s = __builtin_amdgcn_mfma_f32_16x16x32_f16(aK[1], bq1, s, 0, 0, 0);
      // clamp: also scrubs any Inf/NaN (fmaxf/fminf return the non-NaN arg)
      #pragma unroll
      for (int r = 0; r < 4; ++r) s[r] = fminf(fmaxf(s[r], MNEG), 1.0e30f);
      sacc[j] = s;
    }
    if (st == tt){  // diagonal tile: keep s<=t
      #pragma unroll
      for (int j = 0; j < 4; ++j)
        #pragma unroll
        for (int r = 0; r < 4; ++r)
          if (j*16u + l15 > w*16u + quad*4u + (uint)r) sacc[j][r] = MNEG;
    }
    float alpha[4];
    #pragma unroll
    for (int r = 0; r < 4; ++r){
      float v = fmaxf(fmaxf(sacc[0][r], sacc[1][r]), fmaxf(sacc[2][r], sacc[3][r]));
      v = fmaxf(v, __shfl_xor(v, 1));
      v = fmaxf(v, __shfl_xor(v, 2));
      v = fmaxf(v, __shfl_xor(v, 4));
      v = fmaxf(v, __shfl_xor(v, 8));
      float mn = fmaxf(m[r], v);
      alpha[r] = exp2f((m[r] - mn)*L2E);
      m[r] = mn;
    }
    #pragma unroll
    for (int j = 0; j < 4; ++j)
      #pragma unroll
      for (int r = 0; r < 4; ++r)
        sacc[j][r] = exp2f((sacc[j][r] - m[r])*L2E);
    #pragma unroll
    for (int r = 0; r < 4; ++r){
      float s = sacc[0][r] + sacc[1][r] + sacc[2][r] + sacc[3][r];
      s += __shfl_xor(s, 1);
      s += __shfl_xor(s, 2);
      s += __shfl_xor(s, 4);
      s += __shfl_xor(s, 8);
      l[r] = l[r]*alpha[r] + s;
    }
    #pragma unroll
    for (int je = 0; je < 4; ++je)
      #pragma unroll
      for (int r = 0; r < 4; ++r)
        oacc[je][r] *= alpha[r];
    // P: C/D layout -> LDS -> A-operand layout (per-wave region)
    #pragma unroll
    for (int j = 0; j < 4; ++j)
      #pragma unroll
      for (int r = 0; r < 4; ++r)
        pbuf[w][quad*4u + r][j*16u + l15] = f2h(sacc[j][r]);
    __syncthreads();
    f16x8 aP0 = *(const f16x8*)&pbuf[w][l15][quad*8u];
    f16x8 aP1 = *(const f16x8*)&pbuf[w][l15][32u + quad*8u];
    #pragma unroll
    for (int je = 0; je < 4; ++je){
      const ushort* vp = Vt + (size_t)(bh*64u + je*16u + l15)*512u + s0 + quad*8u;
      f16x8 bv0 = ld16(vp);
      f16x8 bv1 = ld16(vp + 32);
      oacc[je] = __builtin_amdgcn_mfma_f32_16x16x32_f16(aP0, bv0, oacc[je], 0, 0, 0);
      oacc[je] = __builtin_amdgcn_mfma_f32_16x16x32_f16(aP1, bv1, oacc[je], 0, 0, 0);
    }
    __syncthreads();
  }
  float inv[4];
  #pragma unroll
  for (int r = 0; r < 4; ++r) inv[r] = 1.0f / l[r];
  #pragma unroll
  for (int je = 0; je < 4; ++je){
    uint e = h*64u + je*16u + l15;
    #pragma unroll
    for (int r = 0; r < 4; ++r){
      uint t = t0 + w*16u + quad*4u + (uint)r;
      Out[(size_t)(b*512u + t)*1024u + e] = f2h(oacc[je][r]*inv[r]);
    }
  }
}

// ---------------- launcher ---------------------------------------------------

extern "C" void kernel_launch(void* const* d_in, const int* in_sizes, int n_in,
                              void* d_out, int out_size, void* d_ws, size_t ws_size,
                              hipStream_t stream){
  const void* x  = d_in[0];
  const void* Wi = d_in[1];
  const void* bi = d_in[2];
  const void* Wk = d_in[3];
  const void* bk = d_in[4];
  const void* Wq = d_in[5];
  const void* bq = d_in[6];
  const void* Wv = d_in[7];
  const void* bv = d_in[8];
  const void* Wo = d_in[9];
  const void* bo = d_in[10];
  char* ws = (char*)d_ws;

  const size_t MB = 1u << 20;
  int*    flag   = (int*)ws;
  float*  bi_f   = (float*)(ws + 4096);                  // 4 KB
  float*  bo_f   = (float*)(ws + 8192);                  // 4 KB
  float*  bqkv_f = (float*)(ws + 12288);                 // 12 KB
  ushort* WiT    = (ushort*)(ws + 32768);                // 2 MB  (fp16)
  ushort* WoT    = (ushort*)(ws + 32768 + 2*MB);         // 2 MB
  ushort* WqkvT  = (ushort*)(ws + 32768 + 4*MB);         // 6 MB
  ushort* xh     = (ushort*)(ws + 32768 + 10*MB);        // 32 MB (dead after GEMM0)
  ushort* kq     = (ushort*)(ws + 32768 + 10*MB);        // 64 MB (overlays xh)
  ushort* hbuf   = (ushort*)(ws + 32768 + 74*MB);        // 32 MB (h, then attn out)
  ushort* Vt     = (ushort*)(ws + 32768 + 106*MB);       // 32 MB -> total ~138 MB

  kdetect<<<dim3(1), dim3(256), 0, stream>>>((const uint*)Wi, flag);
  kbias<<<dim3(20), dim3(256), 0, stream>>>(bi, bo, bk, bq, bv, flag, bi_f, bo_f, bqkv_f);
  ktranspose<<<dim3(4096), dim3(256), 0, stream>>>(Wi, flag, WiT);
  ktranspose<<<dim3(4096), dim3(256), 0, stream>>>(Wo, flag, WoT);
  kqkvpack<<<dim3(12288), dim3(256), 0, stream>>>(Wk, Wq, Wv, flag, WqkvT);
  kcvt_x<<<dim3(8192), dim3(256), 0, stream>>>(x, flag, xh);

  kgemm<0><<<dim3(128, 8),  dim3(256), 0, stream>>>(xh,   WiT,   bi_f,   hbuf, nullptr, nullptr, NTOK, 1024, 1024);
  kgemm<1><<<dim3(128, 24), dim3(256), 0, stream>>>(hbuf, WqkvT, bqkv_f, kq,   Vt,      nullptr, NTOK, 3072, 1024);
  kattn<<<dim3(512, 8), dim3(256), 0, stream>>>(kq, Vt, hbuf);
  kgemm<2><<<dim3(128, 8),  dim3(256), 0, stream>>>(hbuf, WoT,   bo_f,   d_out, nullptr, flag,   NTOK, 1024, 1024);
}

// Round 4
// 522.045 us; speedup vs baseline: 1.0702x; 1.0702x over previous
//
#include <hip/hip_runtime.h>
#include <hip/hip_bf16.h>
#include <stdint.h>

// B=32, T=512, D=1024, H=16, HD=64
#define NTOK 16384

typedef _Float16 f16;
typedef f16   f16x8 __attribute__((ext_vector_type(8)));
typedef float f32x4 __attribute__((ext_vector_type(4)));

__device__ __forceinline__ float bf2f(ushort h){
  union { uint32_t u; float f; } v; v.u = ((uint32_t)h) << 16; return v.f;
}
__device__ __forceinline__ ushort f2bf(float f){
  union { float f; uint32_t u; } v; v.f = f;
  uint32_t u = v.u;
  return (ushort)((u + 0x7FFFu + ((u >> 16) & 1u)) >> 16);  // RNE
}
__device__ __forceinline__ ushort f2h(float f){          // fp32 -> fp16 bits (RNE)
  return __builtin_bit_cast(ushort, (f16)f);
}
__device__ __forceinline__ f16x8 ld16(const ushort* p){  // 8 fp16
  uint4 u = *(const uint4*)p;
  return __builtin_bit_cast(f16x8, u);
}
// dtype-flexible fp32 load: fp32 path direct, bf16 path converts
__device__ __forceinline__ float ldf(const void* p, size_t idx, int isf32){
  if (isf32) return ((const float*)p)[idx];
  return bf2f(((const ushort*)p)[idx]);
}

// stage a 64x64 fp16 tile (row stride strideEl elements, 128B-contiguous rows)
// into packed LDS [64][64] via global_load_lds width-16. ldsbase is the tile
// base; HW adds lane*16B to the wave-uniform LDS address.
__device__ __forceinline__ void stage64(const ushort* g, uint strideEl,
                                        ushort* ldsbase, uint tid){
  uint w = tid >> 6;
  #pragma unroll
  for (int i = 0; i < 2; ++i){
    uint c = i*256u + tid;                        // chunk id (16B units)
    const ushort* gp = g + (size_t)(c >> 3)*strideEl + (c & 7u)*8u;
    ushort* lp = ldsbase + (size_t)(i*256u + w*64u)*8u;   // wave-uniform base
    __builtin_amdgcn_global_load_lds((const __attribute__((address_space(1))) void*)gp,
        (__attribute__((address_space(3))) void*)lp, 16, 0, 0);
  }
}

// ---------------- input dtype detection --------------------------------------
__global__ __launch_bounds__(256) void kdetect(const uint* __restrict__ wi, int* __restrict__ flag){
  __shared__ int cnt;
  if (threadIdx.x == 0) cnt = 0;
  __syncthreads();
  uint w = wi[threadIdx.x];
  uint e = (w >> 7) & 0xFFu;
  if (e >= 100u && e <= 130u) atomicAdd(&cnt, 1);
  __syncthreads();
  if (threadIdx.x == 0) flag[0] = (cnt < 128) ? 1 : 0;
}

// ---------------- bias canonicalization -> fp32 (5120 elements) --------------
__global__ __launch_bounds__(256) void kbias(const void* bi, const void* bo,
                                             const void* bk, const void* bq, const void* bv,
                                             const int* __restrict__ flag,
                                             float* bi_f, float* bo_f, float* bqkv_f){
  int f = flag[0];
  uint id = blockIdx.x*256u + threadIdx.x;   // [0, 5120)
  if (id < 1024u)       bi_f[id]         = ldf(bi, id, f);
  else if (id < 2048u)  bo_f[id - 1024u] = ldf(bo, id - 1024u, f);
  else {
    uint j = id - 2048u;                     // [0,3072): sel*1024 + (h*64+e)
    uint sel = j >> 10, i = j & 1023u;
    const void* src = (sel == 0) ? bk : ((sel == 1) ? bq : bv);
    bqkv_f[j] = ldf(src, i, f);
  }
}

// ---------------- coalesced tiled transpose: out[c][r] = in[r][c], 1024x1024 --
__global__ __launch_bounds__(256) void ktranspose(const void* __restrict__ in,
                                                  const int* __restrict__ flag,
                                                  ushort* __restrict__ out){
  __shared__ float tile[64][65];
  int f = flag[0];
  uint R0 = blockIdx.x*64u, C0 = blockIdx.y*64u, t = threadIdx.x;
  #pragma unroll
  for (int i = 0; i < 16; ++i){
    uint id = i*256u + t, r = id >> 6, c = id & 63u;
    tile[r][c] = ldf(in, (size_t)(R0 + r)*1024u + C0 + c, f);
  }
  __syncthreads();
  #pragma unroll
  for (int i = 0; i < 16; ++i){
    uint id = i*256u + t, r = id >> 6, c = id & 63u;   // r = out-row (C-dim)
    out[(size_t)(C0 + r)*1024u + R0 + c] = f2h(tile[c][r]);
  }
}

// WqkvT[c][d] fp16, c = sel*1024 + h*64 + e ; W[sel] flat = h*65536 + d*64 + e
// per (sel,h): transpose [1024 d][64 e] -> [64 e][1024 d], tiled over d.
__global__ __launch_bounds__(256) void kqkvpack(const void* Wk, const void* Wq, const void* Wv,
                                                const int* __restrict__ flag,
                                                ushort* __restrict__ WqkvT){
  __shared__ float tile[64][65];
  int f = flag[0];
  uint sh = blockIdx.x;                 // sel*16 + h
  uint sel = sh >> 4, h = sh & 15u;
  uint D0 = blockIdx.y*64u, t = threadIdx.x;
  const void* W = (sel == 0) ? Wk : ((sel == 1) ? Wq : Wv);
  #pragma unroll
  for (int i = 0; i < 16; ++i){
    uint id = i*256u + t, r = id >> 6, c = id & 63u;   // r = d-local, c = e
    tile[r][c] = ldf(W, (size_t)h*65536u + (size_t)(D0 + r)*64u + c, f);
  }
  __syncthreads();
  #pragma unroll
  for (int i = 0; i < 16; ++i){
    uint id = i*256u + t, r = id >> 6, c = id & 63u;   // r = e, c = d-local
    WqkvT[(size_t)(sel*1024u + h*64u + r)*1024u + D0 + c] = f2h(tile[c][r]);
  }
}

// x -> canonical fp16 (16M elements, 8 per thread)
__global__ __launch_bounds__(256) void kcvt_x(const void* __restrict__ x,
                                              const int* __restrict__ flag,
                                              ushort* __restrict__ xh){
  int f = flag[0];
  size_t g = (size_t)(blockIdx.x*256u + threadIdx.x)*8u;
  ushort o[8];
  if (f){
    const float* xf = (const float*)x + g;
    #pragma unroll
    for (int i = 0; i < 8; ++i) o[i] = f2h(xf[i]);
  } else {
    const ushort* xb = (const ushort*)x + g;
    #pragma unroll
    for (int i = 0; i < 8; ++i) o[i] = f2h(bf2f(xb[i]));
  }
  *(uint4*)(xh + g) = *(uint4*)o;
}

// ---------------- GEMM: C[M,N] = A[M,K] @ Bt[N,K]^T + bias (fp16, m97) -------
template<int MODE>
__global__ __launch_bounds__(256, 3) void kgemm(const ushort* __restrict__ A, const ushort* __restrict__ Bt,
                                                const float* __restrict__ bias, void* __restrict__ Cv,
                                                ushort* __restrict__ Vt, const int* __restrict__ dtf,
                                                int M, int N, int K){
  __shared__ ushort sA[128*32];
  __shared__ ushort sB[128*32];
  uint tid = threadIdx.x, w = tid >> 6, lane = tid & 63u, quad = lane >> 4, l15 = lane & 15u;
  uint bm = blockIdx.x, bn = blockIdx.y;
  uint wm = w >> 1, wn = w & 1u;
  f32x4 acc[4][4] = {};

  for (int k0 = 0; k0 < K; k0 += 32){
    #pragma unroll
    for (int i = 0; i < 2; ++i){
      uint c   = (w*2u + i)*64u + lane;     // 16B chunk id within tile
      uint row = c >> 2, ko = (c & 3u)*8u;  // [128][32] row-major, 4 chunks/row
      const ushort* gA = A  + (size_t)(bm*128u + row)*K + k0 + ko;
      const ushort* gB = Bt + (size_t)(bn*128u + row)*K + k0 + ko;
      __builtin_amdgcn_global_load_lds((const __attribute__((address_space(1))) void*)gA,
          (__attribute__((address_space(3))) void*)(sA + (w*2u + i)*512u), 16, 0, 0);
      __builtin_amdgcn_global_load_lds((const __attribute__((address_space(1))) void*)gB,
          (__attribute__((address_space(3))) void*)(sB + (w*2u + i)*512u), 16, 0, 0);
    }
    __syncthreads();
    f16x8 aF[4], bF[4];
    #pragma unroll
    for (int i = 0; i < 4; ++i) aF[i] = *(const f16x8*)(sA + (wm*64u + i*16u + l15)*32u + quad*8u);
    #pragma unroll
    for (int j = 0; j < 4; ++j) bF[j] = *(const f16x8*)(sB + (wn*64u + j*16u + l15)*32u + quad*8u);
    #pragma unroll
    for (int i = 0; i < 4; ++i)
      #pragma unroll
      for (int j = 0; j < 4; ++j)
        acc[i][j] = __builtin_amdgcn_mfma_f32_16x16x32_f16(aF[i], bF[j], acc[i][j], 0, 0, 0);
    __syncthreads();
  }
  int f32out = (MODE == 2) ? dtf[0] : 0;
  #pragma unroll
  for (int j = 0; j < 4; ++j){
    uint col = bn*128u + wn*64u + j*16u + l15;
    float bj = bias[col];
    #pragma unroll
    for (int i = 0; i < 4; ++i){
      uint row0 = bm*128u + wm*64u + i*16u + quad*4u;
      #pragma unroll
      for (int r = 0; r < 4; ++r){
        float val = acc[i][j][r] + bj;
        uint row = row0 + r;
        if (MODE == 0){
          ((ushort*)Cv)[(size_t)row*N + col] = f2h(val);
        } else if (MODE == 1){
          if (col < 2048u){
            ((ushort*)Cv)[(size_t)row*2048u + col] = f2h(val);
          } else {
            uint c2 = col - 2048u;           // h*64+e ; row = b*512+s
            Vt[(size_t)(((row >> 9)*16u + (c2 >> 6))*64u + (c2 & 63u))*512u + (row & 511u)] = f2h(val);
          }
        } else {
          if (f32out) ((float*)Cv)[(size_t)row*N + col] = val;
          else        ((ushort*)Cv)[(size_t)row*N + col] = f2bf(val);
        }
      }
    }
  }
}

// ---------------- fused attention ("transposed" causal, flash-style) ---------
// S[t,s] = K[t,:]·Q[s,:], keep s<=t, softmax over s, O[t,:] = sum_s P[t,s]V[s,:]
// kq: fp16 [16384][2048] (k cols 0..1023, q cols 1024..2047);
// Vt: fp16 [(b*16+h)*64+e][512]
// LDS-staged tiles (shared by all 4 waves), ping-pong prefetch.
__global__ __launch_bounds__(256, 4) void kattn(const ushort* __restrict__ kq,
                                                const ushort* __restrict__ Vt,
                                                ushort* __restrict__ Out){
  __shared__ ushort sQ[2][64*64];          // [s-local][d]   16 KB
  __shared__ ushort sV[2][64*64];          // [e][s-local]   16 KB
  __shared__ ushort pbuf[4][16][64];       // per-wave P; also K staging  8 KB
  uint tid = threadIdx.x, w = tid >> 6, lane = tid & 63u, quad = lane >> 4, l15 = lane & 15u;
  uint bh = blockIdx.x, tt = blockIdx.y;
  uint b = bh >> 4, h = bh & 15u;
  uint t0 = tt*64u;
  const float L2E = 1.44269504088896340736f;
  const float MNEG = -1.0e30f;

  // stage K tile [t-local][d] into pbuf, Q0/V0 into buf 0
  stage64(kq + (size_t)(b*512u + t0)*2048u + h*64u, 2048u, (ushort*)pbuf, tid);
  stage64(kq + (size_t)(b*512u)*2048u + 1024u + h*64u, 2048u, sQ[0], tid);   // s0=0
  stage64(Vt + (size_t)(bh*64u)*512u, 512u, sV[0], tid);
  __syncthreads();

  f16x8 aK[2];  // K rows for this wave's 16 t's (A-operand, resident)
  {
    const ushort* kp = (const ushort*)pbuf + (size_t)(w*16u + l15)*64u + quad*8u;
    aK[0] = ld16(kp);
    aK[1] = ld16(kp + 32);
  }
  float m[4], l[4];
  f32x4 oacc[4];
  #pragma unroll
  for (int r = 0; r < 4; ++r){ m[r] = MNEG; l[r] = 0.f; }
  #pragma unroll
  for (int je = 0; je < 4; ++je) oacc[je] = (f32x4){0.f, 0.f, 0.f, 0.f};

  for (uint st = 0; st <= tt; ++st){
    uint cur = st & 1u;
    if (st) __syncthreads();               // staged bufs[cur] ready; prev PV done
    f32x4 sacc[4];
    #pragma unroll
    for (int j = 0; j < 4; ++j){
      const ushort* qp = sQ[cur] + (size_t)(j*16u + l15)*64u + quad*8u;
      f16x8 bq0 = ld16(qp);
      f16x8 bq1 = ld16(qp + 32);
      f32x4 s = (f32x4){0.f, 0.f, 0.f, 0.f};
      s = __builtin_amdgcn_mfma_f32_16x16x32_f16(aK[0], bq0, s, 0, 0, 0);
      s = __builtin_amdgcn_mfma_f32_16x16x32_f16(aK[1], bq1, s, 0, 0, 0);
      #pragma unroll
      for (int r = 0; r < 4; ++r) s[r] = fminf(fmaxf(s[r], MNEG), 1.0e30f);
      sacc[j] = s;
    }
    if (st == tt){  // diagonal tile: keep s<=t
      #pragma unroll
      for (int j = 0; j < 4; ++j)
        #pragma unroll
        for (int r = 0; r < 4; ++r)
          if (j*16u + l15 > w*16u + quad*4u + (uint)r) sacc[j][r] = MNEG;
    }
    float alpha[4];
    #pragma unroll
    for (int r = 0; r < 4; ++r){
      float v = fmaxf(fmaxf(sacc[0][r], sacc[1][r]), fmaxf(sacc[2][r], sacc[3][r]));
      v = fmaxf(v, __shfl_xor(v, 1));
      v = fmaxf(v, __shfl_xor(v, 2));
      v = fmaxf(v, __shfl_xor(v, 4));
      v = fmaxf(v, __shfl_xor(v, 8));
      float mn = fmaxf(m[r], v);
      alpha[r] = exp2f((m[r] - mn)*L2E);
      m[r] = mn;
    }
    #pragma unroll
    for (int j = 0; j < 4; ++j)
      #pragma unroll
      for (int r = 0; r < 4; ++r)
        sacc[j][r] = exp2f((sacc[j][r] - m[r])*L2E);
    #pragma unroll
    for (int r = 0; r < 4; ++r){
      float s = sacc[0][r] + sacc[1][r] + sacc[2][r] + sacc[3][r];
      s += __shfl_xor(s, 1);
      s += __shfl_xor(s, 2);
      s += __shfl_xor(s, 4);
      s += __shfl_xor(s, 8);
      l[r] = l[r]*alpha[r] + s;
    }
    #pragma unroll
    for (int je = 0; je < 4; ++je)
      #pragma unroll
      for (int r = 0; r < 4; ++r)
        oacc[je][r] *= alpha[r];
    // P: C/D layout -> LDS (per-wave region)
    #pragma unroll
    for (int j = 0; j < 4; ++j)
      #pragma unroll
      for (int r = 0; r < 4; ++r)
        pbuf[w][quad*4u + r][j*16u + l15] = f2h(sacc[j][r]);
    __syncthreads();                        // pbuf ordering; no vmem pending
    // prefetch next tiles AFTER the barrier so its vmcnt-drain doesn't stall
    if (st < tt){
      uint s1 = (st + 1u)*64u;
      stage64(kq + (size_t)(b*512u + s1)*2048u + 1024u + h*64u, 2048u, sQ[1u - cur], tid);
      stage64(Vt + (size_t)(bh*64u)*512u + s1, 512u, sV[1u - cur], tid);
    }
    f16x8 aP0 = *(const f16x8*)&pbuf[w][l15][quad*8u];
    f16x8 aP1 = *(const f16x8*)&pbuf[w][l15][32u + quad*8u];
    #pragma unroll
    for (int je = 0; je < 4; ++je){
      const ushort* vp = sV[cur] + (size_t)(je*16u + l15)*64u + quad*8u;
      f16x8 bv0 = ld16(vp);
      f16x8 bv1 = ld16(vp + 32);
      oacc[je] = __builtin_amdgcn_mfma_f32_16x16x32_f16(aP0, bv0, oacc[je], 0, 0, 0);
      oacc[je] = __builtin_amdgcn_mfma_f32_16x16x32_f16(aP1, bv1, oacc[je], 0, 0, 0);
    }
  }
  float inv[4];
  #pragma unroll
  for (int r = 0; r < 4; ++r) inv[r] = 1.0f / l[r];
  #pragma unroll
  for (int je = 0; je < 4; ++je){
    uint e = h*64u + je*16u + l15;
    #pragma unroll
    for (int r = 0; r < 4; ++r){
      uint t = t0 + w*16u + quad*4u + (uint)r;
      Out[(size_t)(b*512u + t)*1024u + e] = f2h(oacc[je][r]*inv[r]);
    }
  }
}

// ---------------- launcher ---------------------------------------------------

extern "C" void kernel_launch(void* const* d_in, const int* in_sizes, int n_in,
                              void* d_out, int out_size, void* d_ws, size_t ws_size,
                              hipStream_t stream){
  const void* x  = d_in[0];
  const void* Wi = d_in[1];
  const void* bi = d_in[2];
  const void* Wk = d_in[3];
  const void* bk = d_in[4];
  const void* Wq = d_in[5];
  const void* bq = d_in[6];
  const void* Wv = d_in[7];
  const void* bv = d_in[8];
  const void* Wo = d_in[9];
  const void* bo = d_in[10];
  char* ws = (char*)d_ws;

  const size_t MB = 1u << 20;
  int*    flag   = (int*)ws;
  float*  bi_f   = (float*)(ws + 4096);                  // 4 KB
  float*  bo_f   = (float*)(ws + 8192);                  // 4 KB
  float*  bqkv_f = (float*)(ws + 12288);                 // 12 KB
  ushort* WiT    = (ushort*)(ws + 32768);                // 2 MB  (fp16)
  ushort* WoT    = (ushort*)(ws + 32768 + 2*MB);         // 2 MB
  ushort* WqkvT  = (ushort*)(ws + 32768 + 4*MB);         // 6 MB
  ushort* xh     = (ushort*)(ws + 32768 + 10*MB);        // 32 MB (dead after GEMM0)
  ushort* kq     = (ushort*)(ws + 32768 + 10*MB);        // 64 MB (overlays xh)
  ushort* hbuf   = (ushort*)(ws + 32768 + 74*MB);        // 32 MB (h, then attn out)
  ushort* Vt     = (ushort*)(ws + 32768 + 106*MB);       // 32 MB -> total ~138 MB

  kdetect<<<dim3(1), dim3(256), 0, stream>>>((const uint*)Wi, flag);
  kbias<<<dim3(20), dim3(256), 0, stream>>>(bi, bo, bk, bq, bv, flag, bi_f, bo_f, bqkv_f);
  ktranspose<<<dim3(16, 16), dim3(256), 0, stream>>>(Wi, flag, WiT);
  ktranspose<<<dim3(16, 16), dim3(256), 0, stream>>>(Wo, flag, WoT);
  kqkvpack<<<dim3(48, 16), dim3(256), 0, stream>>>(Wk, Wq, Wv, flag, WqkvT);
  kcvt_x<<<dim3(8192), dim3(256), 0, stream>>>(x, flag, xh);

  kgemm<0><<<dim3(128, 8),  dim3(256), 0, stream>>>(xh,   WiT,   bi_f,   hbuf, nullptr, nullptr, NTOK, 1024, 1024);
  kgemm<1><<<dim3(128, 24), dim3(256), 0, stream>>>(hbuf, WqkvT, bqkv_f, kq,   Vt,      nullptr, NTOK, 3072, 1024);
  kattn<<<dim3(512, 8), dim3(256), 0, stream>>>(kq, Vt, hbuf);
  kgemm<2><<<dim3(128, 8),  dim3(256), 0, stream>>>(hbuf, WoT,   bo_f,   d_out, nullptr, flag,   NTOK, 1024, 1024);
}

// Round 5
// 498.804 us; speedup vs baseline: 1.1200x; 1.0466x over previous
//
#include <hip/hip_runtime.h>
#include <hip/hip_bf16.h>
#include <stdint.h>

// B=32, T=512, D=1024, H=16, HD=64
#define NTOK 16384

typedef _Float16 f16;
typedef f16   f16x8 __attribute__((ext_vector_type(8)));
typedef float f32x4 __attribute__((ext_vector_type(4)));

__device__ __forceinline__ float bf2f(ushort h){
  union { uint32_t u; float f; } v; v.u = ((uint32_t)h) << 16; return v.f;
}
__device__ __forceinline__ ushort f2bf(float f){
  union { float f; uint32_t u; } v; v.f = f;
  uint32_t u = v.u;
  return (ushort)((u + 0x7FFFu + ((u >> 16) & 1u)) >> 16);  // RNE
}
__device__ __forceinline__ ushort f2h(float f){          // fp32 -> fp16 bits (RNE)
  return __builtin_bit_cast(ushort, (f16)f);
}
__device__ __forceinline__ f16x8 ld16(const ushort* p){  // 8 fp16
  uint4 u = *(const uint4*)p;
  return __builtin_bit_cast(f16x8, u);
}
// dtype-flexible fp32 load: fp32 path direct, bf16 path converts
__device__ __forceinline__ float ldf(const void* p, size_t idx, int isf32){
  if (isf32) return ((const float*)p)[idx];
  return bf2f(((const ushort*)p)[idx]);
}

// XOR-swizzled 64x64 fp16 tile in LDS: element (row,col) lives at
//   row*64 + ((col>>3) ^ (row&7))*8 + (col&7)
// -> b128 fragment reads hit 8 distinct bank groups (the b128 floor) instead
//    of 4 (16-way serialization) with the identity layout.
__device__ __forceinline__ const ushort* swz(const ushort* base, uint row, uint chunk){
  return base + (size_t)row*64u + (size_t)((chunk ^ (row & 7u))*8u);
}

// stage a 64x64 fp16 tile (row stride strideEl, 128B-contiguous rows) into
// swizzled LDS via global_load_lds width-16. Dest chunk is forced to be
// wave-uniform-base + lane*16B; we permute the SOURCE chunk instead (free).
__device__ __forceinline__ void stage64(const ushort* g, uint strideEl,
                                        ushort* ldsbase, uint tid){
  uint w = tid >> 6;
  #pragma unroll
  for (int i = 0; i < 2; ++i){
    uint lc  = i*256u + tid;               // dest chunk id (16B units)
    uint row = lc >> 3, cp = lc & 7u;
    uint c   = cp ^ (row & 7u);            // swizzled source chunk
    const ushort* gp = g + (size_t)row*strideEl + c*8u;
    ushort* lp = ldsbase + (size_t)(i*256u + w*64u)*8u;   // wave-uniform base
    __builtin_amdgcn_global_load_lds((const __attribute__((address_space(1))) void*)gp,
        (__attribute__((address_space(3))) void*)lp, 16, 0, 0);
  }
}

// ---------------- input dtype detection --------------------------------------
__global__ __launch_bounds__(256) void kdetect(const uint* __restrict__ wi, int* __restrict__ flag){
  __shared__ int cnt;
  if (threadIdx.x == 0) cnt = 0;
  __syncthreads();
  uint w = wi[threadIdx.x];
  uint e = (w >> 7) & 0xFFu;
  if (e >= 100u && e <= 130u) atomicAdd(&cnt, 1);
  __syncthreads();
  if (threadIdx.x == 0) flag[0] = (cnt < 128) ? 1 : 0;
}

// ---------------- bias canonicalization -> fp32 (5120 elements) --------------
__global__ __launch_bounds__(256) void kbias(const void* bi, const void* bo,
                                             const void* bk, const void* bq, const void* bv,
                                             const int* __restrict__ flag,
                                             float* bi_f, float* bo_f, float* bqkv_f){
  int f = flag[0];
  uint id = blockIdx.x*256u + threadIdx.x;   // [0, 5120)
  if (id < 1024u)       bi_f[id]         = ldf(bi, id, f);
  else if (id < 2048u)  bo_f[id - 1024u] = ldf(bo, id - 1024u, f);
  else {
    uint j = id - 2048u;                     // [0,3072): sel*1024 + (h*64+e)
    uint sel = j >> 10, i = j & 1023u;
    const void* src = (sel == 0) ? bk : ((sel == 1) ? bq : bv);
    bqkv_f[j] = ldf(src, i, f);
  }
}

// ---------------- coalesced tiled transpose: out[c][r] = in[r][c], 1024x1024 --
__global__ __launch_bounds__(256) void ktranspose(const void* __restrict__ in,
                                                  const int* __restrict__ flag,
                                                  ushort* __restrict__ out){
  __shared__ float tile[64][65];
  int f = flag[0];
  uint R0 = blockIdx.x*64u, C0 = blockIdx.y*64u, t = threadIdx.x;
  #pragma unroll
  for (int i = 0; i < 16; ++i){
    uint id = i*256u + t, r = id >> 6, c = id & 63u;
    tile[r][c] = ldf(in, (size_t)(R0 + r)*1024u + C0 + c, f);
  }
  __syncthreads();
  #pragma unroll
  for (int i = 0; i < 16; ++i){
    uint id = i*256u + t, r = id >> 6, c = id & 63u;   // r = out-row (C-dim)
    out[(size_t)(C0 + r)*1024u + R0 + c] = f2h(tile[c][r]);
  }
}

// WqkvT[c][d] fp16, c = sel*1024 + h*64 + e ; W[sel] flat = h*65536 + d*64 + e
__global__ __launch_bounds__(256) void kqkvpack(const void* Wk, const void* Wq, const void* Wv,
                                                const int* __restrict__ flag,
                                                ushort* __restrict__ WqkvT){
  __shared__ float tile[64][65];
  int f = flag[0];
  uint sh = blockIdx.x;                 // sel*16 + h
  uint sel = sh >> 4, h = sh & 15u;
  uint D0 = blockIdx.y*64u, t = threadIdx.x;
  const void* W = (sel == 0) ? Wk : ((sel == 1) ? Wq : Wv);
  #pragma unroll
  for (int i = 0; i < 16; ++i){
    uint id = i*256u + t, r = id >> 6, c = id & 63u;   // r = d-local, c = e
    tile[r][c] = ldf(W, (size_t)h*65536u + (size_t)(D0 + r)*64u + c, f);
  }
  __syncthreads();
  #pragma unroll
  for (int i = 0; i < 16; ++i){
    uint id = i*256u + t, r = id >> 6, c = id & 63u;   // r = e, c = d-local
    WqkvT[(size_t)(sel*1024u + h*64u + r)*1024u + D0 + c] = f2h(tile[c][r]);
  }
}

// x -> canonical fp16 (16M elements, 8 per thread)
__global__ __launch_bounds__(256) void kcvt_x(const void* __restrict__ x,
                                              const int* __restrict__ flag,
                                              ushort* __restrict__ xh){
  int f = flag[0];
  size_t g = (size_t)(blockIdx.x*256u + threadIdx.x)*8u;
  ushort o[8];
  if (f){
    const float* xf = (const float*)x + g;
    #pragma unroll
    for (int i = 0; i < 8; ++i) o[i] = f2h(xf[i]);
  } else {
    const ushort* xb = (const ushort*)x + g;
    #pragma unroll
    for (int i = 0; i < 8; ++i) o[i] = f2h(bf2f(xb[i]));
  }
  *(uint4*)(xh + g) = *(uint4*)o;
}

// ---------------- GEMM: C[M,N] = A[M,K] @ Bt[N,K]^T + bias (fp16, m97) -------
// launch_bounds(256,4): VGPR 56 + AGPR 64 = 120 <= 128 -> 4 blocks/CU; the
// N=1024 GEMMs (1024 blocks) then run in exactly ONE dispatch round.
template<int MODE>
__global__ __launch_bounds__(256, 4) void kgemm(const ushort* __restrict__ A, const ushort* __restrict__ Bt,
                                                const float* __restrict__ bias, void* __restrict__ Cv,
                                                ushort* __restrict__ Vt, const int* __restrict__ dtf,
                                                int M, int N, int K){
  __shared__ ushort sA[128*32];
  __shared__ ushort sB[128*32];
  uint tid = threadIdx.x, w = tid >> 6, lane = tid & 63u, quad = lane >> 4, l15 = lane & 15u;
  uint bm = blockIdx.x, bn = blockIdx.y;
  uint wm = w >> 1, wn = w & 1u;
  f32x4 acc[4][4] = {};

  for (int k0 = 0; k0 < K; k0 += 32){
    #pragma unroll
    for (int i = 0; i < 2; ++i){
      uint c   = (w*2u + i)*64u + lane;     // 16B chunk id within tile
      uint row = c >> 2, ko = (c & 3u)*8u;  // [128][32] row-major, 4 chunks/row
      const ushort* gA = A  + (size_t)(bm*128u + row)*K + k0 + ko;
      const ushort* gB = Bt + (size_t)(bn*128u + row)*K + k0 + ko;
      __builtin_amdgcn_global_load_lds((const __attribute__((address_space(1))) void*)gA,
          (__attribute__((address_space(3))) void*)(sA + (w*2u + i)*512u), 16, 0, 0);
      __builtin_amdgcn_global_load_lds((const __attribute__((address_space(1))) void*)gB,
          (__attribute__((address_space(3))) void*)(sB + (w*2u + i)*512u), 16, 0, 0);
    }
    __syncthreads();
    f16x8 aF[4], bF[4];
    #pragma unroll
    for (int i = 0; i < 4; ++i) aF[i] = *(const f16x8*)(sA + (wm*64u + i*16u + l15)*32u + quad*8u);
    #pragma unroll
    for (int j = 0; j < 4; ++j) bF[j] = *(const f16x8*)(sB + (wn*64u + j*16u + l15)*32u + quad*8u);
    #pragma unroll
    for (int i = 0; i < 4; ++i)
      #pragma unroll
      for (int j = 0; j < 4; ++j)
        acc[i][j] = __builtin_amdgcn_mfma_f32_16x16x32_f16(aF[i], bF[j], acc[i][j], 0, 0, 0);
    __syncthreads();
  }
  int f32out = (MODE == 2) ? dtf[0] : 0;
  #pragma unroll
  for (int j = 0; j < 4; ++j){
    uint col = bn*128u + wn*64u + j*16u + l15;
    float bj = bias[col];
    #pragma unroll
    for (int i = 0; i < 4; ++i){
      uint row0 = bm*128u + wm*64u + i*16u + quad*4u;
      #pragma unroll
      for (int r = 0; r < 4; ++r){
        float val = acc[i][j][r] + bj;
        uint row = row0 + r;
        if (MODE == 0){
          ((ushort*)Cv)[(size_t)row*N + col] = f2h(val);
        } else if (MODE == 1){
          if (col < 2048u){
            ((ushort*)Cv)[(size_t)row*2048u + col] = f2h(val);
          } else {
            uint c2 = col - 2048u;           // h*64+e ; row = b*512+s
            Vt[(size_t)(((row >> 9)*16u + (c2 >> 6))*64u + (c2 & 63u))*512u + (row & 511u)] = f2h(val);
          }
        } else {
          if (f32out) ((float*)Cv)[(size_t)row*N + col] = val;
          else        ((ushort*)Cv)[(size_t)row*N + col] = f2bf(val);
        }
      }
    }
  }
}

// ---------------- fused attention ("transposed" causal, flash-style) ---------
// S[t,s] = K[t,:]·Q[s,:], keep s<=t, softmax over s, O[t,:] = sum_s P[t,s]V[s,:]
// kq: fp16 [16384][2048]; Vt: fp16 [(b*16+h)*64+e][512]
// ONE barrier per s-iter (pbuf is wave-private); prefetch issued right after
// the barrier (full-iteration latency cover); XOR-swizzled LDS tiles.
__global__ __launch_bounds__(256, 4) void kattn(const ushort* __restrict__ kq,
                                                const ushort* __restrict__ Vt,
                                                ushort* __restrict__ Out){
  __shared__ ushort sQ[2][64*64];          // [s-local][d] swizzled   16 KB
  __shared__ ushort sV[2][64*64];          // [e][s-local] swizzled   16 KB
  __shared__ ushort pbuf[4][16*64];        // per-wave P (swizzled); K staging  8 KB
  uint tid = threadIdx.x, w = tid >> 6, lane = tid & 63u, quad = lane >> 4, l15 = lane & 15u;
  uint bh = blockIdx.x, tt = blockIdx.y;
  uint b = bh >> 4, h = bh & 15u;
  uint t0 = tt*64u;
  const float L2E = 1.44269504088896340736f;
  const float MNEG = -1.0e30f;

  // stage K tile [t-local][d] into pbuf, Q0/V0 into buf 0 (all swizzled)
  stage64(kq + (size_t)(b*512u + t0)*2048u + h*64u, 2048u, (ushort*)pbuf, tid);
  stage64(kq + (size_t)(b*512u)*2048u + 1024u + h*64u, 2048u, sQ[0], tid);   // s0=0
  stage64(Vt + (size_t)(bh*64u)*512u, 512u, sV[0], tid);
  __syncthreads();

  f16x8 aK[2];  // K rows for this wave's 16 t's (wave-own pbuf rows)
  aK[0] = ld16(swz((const ushort*)pbuf, w*16u + l15, quad));
  aK[1] = ld16(swz((const ushort*)pbuf, w*16u + l15, 4u + quad));

  float m[4], l[4];
  f32x4 oacc[4];
  #pragma unroll
  for (int r = 0; r < 4; ++r){ m[r] = MNEG; l[r] = 0.f; }
  #pragma unroll
  for (int je = 0; je < 4; ++je) oacc[je] = (f32x4){0.f, 0.f, 0.f, 0.f};

  ushort* pw = (ushort*)pbuf + w*1024u;    // wave-private P region

  for (uint st = 0; st <= tt; ++st){
    uint cur = st & 1u;
    if (st) __syncthreads();               // staged bufs[cur] ready (vmcnt drained)
    if (st < tt){                          // prefetch st+1 with full-iter cover
      uint s1 = (st + 1u)*64u;
      stage64(kq + (size_t)(b*512u + s1)*2048u + 1024u + h*64u, 2048u, sQ[1u - cur], tid);
      stage64(Vt + (size_t)(bh*64u)*512u + s1, 512u, sV[1u - cur], tid);
    }
    f32x4 sacc[4];
    #pragma unroll
    for (int j = 0; j < 4; ++j){
      f16x8 bq0 = ld16(swz(sQ[cur], j*16u + l15, quad));
      f16x8 bq1 = ld16(swz(sQ[cur], j*16u + l15, 4u + quad));
      f32x4 s = (f32x4){0.f, 0.f, 0.f, 0.f};
      s = __builtin_amdgcn_mfma_f32_16x16x32_f16(aK[0], bq0, s, 0, 0, 0);
      s = __builtin_amdgcn_mfma_f32_16x16x32_f16(aK[1], bq1, s, 0, 0, 0);
      #pragma unroll
      for (int r = 0; r < 4; ++r) s[r] = fminf(fmaxf(s[r], MNEG), 1.0e30f);
      sacc[j] = s;
    }
    if (st == tt){  // diagonal tile: keep s<=t
      #pragma unroll
      for (int j = 0; j < 4; ++j)
        #pragma unroll
        for (int r = 0; r < 4; ++r)
          if (j*16u + l15 > w*16u + quad*4u + (uint)r) sacc[j][r] = MNEG;
    }
    float alpha[4];
    #pragma unroll
    for (int r = 0; r < 4; ++r){
      float v = fmaxf(fmaxf(sacc[0][r], sacc[1][r]), fmaxf(sacc[2][r], sacc[3][r]));
      v = fmaxf(v, __shfl_xor(v, 1));
      v = fmaxf(v, __shfl_xor(v, 2));
      v = fmaxf(v, __shfl_xor(v, 4));
      v = fmaxf(v, __shfl_xor(v, 8));
      float mn = fmaxf(m[r], v);
      alpha[r] = exp2f((m[r] - mn)*L2E);
      m[r] = mn;
    }
    #pragma unroll
    for (int j = 0; j < 4; ++j)
      #pragma unroll
      for (int r = 0; r < 4; ++r)
        sacc[j][r] = exp2f((sacc[j][r] - m[r])*L2E);
    #pragma unroll
    for (int r = 0; r < 4; ++r){
      float s = sacc[0][r] + sacc[1][r] + sacc[2][r] + sacc[3][r];
      s += __shfl_xor(s, 1);
      s += __shfl_xor(s, 2);
      s += __shfl_xor(s, 4);
      s += __shfl_xor(s, 8);
      l[r] = l[r]*alpha[r] + s;
    }
    #pragma unroll
    for (int je = 0; je < 4; ++je)
      #pragma unroll
      for (int r = 0; r < 4; ++r)
        oacc[je][r] *= alpha[r];
    // P: C/D layout -> wave-private swizzled LDS -> A-operand frags (no barrier)
    #pragma unroll
    for (int j = 0; j < 4; ++j)
      #pragma unroll
      for (int r = 0; r < 4; ++r){
        uint t = quad*4u + (uint)r;
        pw[t*64u + (((j*2u + (l15 >> 3)) ^ (t & 7u))*8u) + (l15 & 7u)] = f2h(sacc[j][r]);
      }
    f16x8 aP0 = ld16(swz(pw, l15, quad));
    f16x8 aP1 = ld16(swz(pw, l15, 4u + quad));
    #pragma unroll
    for (int je = 0; je < 4; ++je){
      f16x8 bv0 = ld16(swz(sV[cur], je*16u + l15, quad));
      f16x8 bv1 = ld16(swz(sV[cur], je*16u + l15, 4u + quad));
      oacc[je] = __builtin_amdgcn_mfma_f32_16x16x32_f16(aP0, bv0, oacc[je], 0, 0, 0);
      oacc[je] = __builtin_amdgcn_mfma_f32_16x16x32_f16(aP1, bv1, oacc[je], 0, 0, 0);
    }
  }
  float inv[4];
  #pragma unroll
  for (int r = 0; r < 4; ++r) inv[r] = 1.0f / l[r];
  #pragma unroll
  for (int je = 0; je < 4; ++je){
    uint e = h*64u + je*16u + l15;
    #pragma unroll
    for (int r = 0; r < 4; ++r){
      uint t = t0 + w*16u + quad*4u + (uint)r;
      Out[(size_t)(b*512u + t)*1024u + e] = f2h(oacc[je][r]*inv[r]);
    }
  }
}

// ---------------- launcher ---------------------------------------------------

extern "C" void kernel_launch(void* const* d_in, const int* in_sizes, int n_in,
                              void* d_out, int out_size, void* d_ws, size_t ws_size,
                              hipStream_t stream){
  const void* x  = d_in[0];
  const void* Wi = d_in[1];
  const void* bi = d_in[2];
  const void* Wk = d_in[3];
  const void* bk = d_in[4];
  const void* Wq = d_in[5];
  const void* bq = d_in[6];
  const void* Wv = d_in[7];
  const void* bv = d_in[8];
  const void* Wo = d_in[9];
  const void* bo = d_in[10];
  char* ws = (char*)d_ws;

  const size_t MB = 1u << 20;
  int*    flag   = (int*)ws;
  float*  bi_f   = (float*)(ws + 4096);                  // 4 KB
  float*  bo_f   = (float*)(ws + 8192);                  // 4 KB
  float*  bqkv_f = (float*)(ws + 12288);                 // 12 KB
  ushort* WiT    = (ushort*)(ws + 32768);                // 2 MB  (fp16)
  ushort* WoT    = (ushort*)(ws + 32768 + 2*MB);         // 2 MB
  ushort* WqkvT  = (ushort*)(ws + 32768 + 4*MB);         // 6 MB
  ushort* xh     = (ushort*)(ws + 32768 + 10*MB);        // 32 MB (dead after GEMM0)
  ushort* kq     = (ushort*)(ws + 32768 + 10*MB);        // 64 MB (overlays xh)
  ushort* hbuf   = (ushort*)(ws + 32768 + 74*MB);        // 32 MB (h, then attn out)
  ushort* Vt     = (ushort*)(ws + 32768 + 106*MB);       // 32 MB -> total ~138 MB

  kdetect<<<dim3(1), dim3(256), 0, stream>>>((const uint*)Wi, flag);
  kbias<<<dim3(20), dim3(256), 0, stream>>>(bi, bo, bk, bq, bv, flag, bi_f, bo_f, bqkv_f);
  ktranspose<<<dim3(16, 16), dim3(256), 0, stream>>>(Wi, flag, WiT);
  ktranspose<<<dim3(16, 16), dim3(256), 0, stream>>>(Wo, flag, WoT);
  kqkvpack<<<dim3(48, 16), dim3(256), 0, stream>>>(Wk, Wq, Wv, flag, WqkvT);
  kcvt_x<<<dim3(8192), dim3(256), 0, stream>>>(x, flag, xh);

  kgemm<0><<<dim3(128, 8),  dim3(256), 0, stream>>>(xh,   WiT,   bi_f,   hbuf, nullptr, nullptr, NTOK, 1024, 1024);
  kgemm<1><<<dim3(128, 24), dim3(256), 0, stream>>>(hbuf, WqkvT, bqkv_f, kq,   Vt,      nullptr, NTOK, 3072, 1024);
  kattn<<<dim3(512, 8), dim3(256), 0, stream>>>(kq, Vt, hbuf);
  kgemm<2><<<dim3(128, 8),  dim3(256), 0, stream>>>(hbuf, WoT,   bo_f,   d_out, nullptr, flag,   NTOK, 1024, 1024);
}